// Round 2
// baseline (351.668 us; speedup 1.0000x reference)
//
#include <hip/hip_runtime.h>

#define BB 8
#define NN 2048
#define FIN 256
#define FO 64

typedef short short8_t __attribute__((ext_vector_type(8)));
typedef float float4_t __attribute__((ext_vector_type(4)));

__device__ __forceinline__ unsigned short f2bf(float x) {
  unsigned int u = __float_as_uint(x);
  unsigned int r = (u + 0x7fffu + ((u >> 16) & 1u)) >> 16;
  return (unsigned short)r;
}

// ---------------- K1: Wh = h@W ; f1 = Wh@a1 ; f2 = Wh@a2 ; V = Wh*level ----
// fp32 in/out. grid 256 blocks (b, 64-row tile), 256 threads, 4x4 reg tile.
__global__ __launch_bounds__(256) void k1_gemm(
    const float* __restrict__ h,
    const float* __restrict__ level,
    const float* __restrict__ W,
    const float* __restrict__ a,
    float* __restrict__ V, float* __restrict__ f1, float* __restrict__ f2)
{
  __shared__ float hs[64 * 65];     // [row][f], stride 65 (bank-safe reads)
  __shared__ float wsm[64 * 64];    // [f][o]
  __shared__ float parts[2 * 1040];
  int t = threadIdx.x;
  int b = blockIdx.x >> 5;
  int i0 = (blockIdx.x & 31) * 64;
  int ti = t & 15, to = t >> 4;
  int srow = t >> 2;
  int sf0 = (t & 3) * 16;
  float acc[4][4] = {};

  for (int fc = 0; fc < FIN; fc += 64) {
    const float* hp = h + (size_t)(b * NN + i0 + srow) * FIN + fc + sf0;
    float4 h0 = *(const float4*)hp;
    float4 h1 = *(const float4*)(hp + 4);
    float4 h2 = *(const float4*)(hp + 8);
    float4 h3 = *(const float4*)(hp + 12);
    float* hd = &hs[srow * 65 + sf0];
    hd[0] = h0.x; hd[1] = h0.y; hd[2] = h0.z; hd[3] = h0.w;
    hd[4] = h1.x; hd[5] = h1.y; hd[6] = h1.z; hd[7] = h1.w;
    hd[8] = h2.x; hd[9] = h2.y; hd[10] = h2.z; hd[11] = h2.w;
    hd[12] = h3.x; hd[13] = h3.y; hd[14] = h3.z; hd[15] = h3.w;

    const float* wp = W + (size_t)(fc + srow) * FO + sf0;
    float4 w0 = *(const float4*)wp;
    float4 w1 = *(const float4*)(wp + 4);
    float4 w2 = *(const float4*)(wp + 8);
    float4 w3 = *(const float4*)(wp + 12);
    float* wd = &wsm[srow * 64 + sf0];
    *(float4*)(wd + 0) = w0; *(float4*)(wd + 4) = w1;
    *(float4*)(wd + 8) = w2; *(float4*)(wd + 12) = w3;
    __syncthreads();

    #pragma unroll 4
    for (int f = 0; f < 64; ++f) {
      float hv0 = hs[(ti * 4 + 0) * 65 + f];
      float hv1 = hs[(ti * 4 + 1) * 65 + f];
      float hv2 = hs[(ti * 4 + 2) * 65 + f];
      float hv3 = hs[(ti * 4 + 3) * 65 + f];
      float4 wv = *(const float4*)&wsm[f * 64 + to * 4];
      acc[0][0] += hv0 * wv.x; acc[0][1] += hv0 * wv.y; acc[0][2] += hv0 * wv.z; acc[0][3] += hv0 * wv.w;
      acc[1][0] += hv1 * wv.x; acc[1][1] += hv1 * wv.y; acc[1][2] += hv1 * wv.z; acc[1][3] += hv1 * wv.w;
      acc[2][0] += hv2 * wv.x; acc[2][1] += hv2 * wv.y; acc[2][2] += hv2 * wv.z; acc[2][3] += hv2 * wv.w;
      acc[3][0] += hv3 * wv.x; acc[3][1] += hv3 * wv.y; acc[3][2] += hv3 * wv.z; acc[3][3] += hv3 * wv.w;
    }
    __syncthreads();
  }

  float a1f0 = a[to * 4 + 0], a1f1 = a[to * 4 + 1];
  float a1f2 = a[to * 4 + 2], a1f3 = a[to * 4 + 3];
  float a2f0 = a[64 + to * 4 + 0], a2f1 = a[64 + to * 4 + 1];
  float a2f2 = a[64 + to * 4 + 2], a2f3 = a[64 + to * 4 + 3];
  #pragma unroll
  for (int r = 0; r < 4; ++r) {
    float p1 = acc[r][0] * a1f0 + acc[r][1] * a1f1 + acc[r][2] * a1f2 + acc[r][3] * a1f3;
    float p2 = acc[r][0] * a2f0 + acc[r][1] * a2f1 + acc[r][2] * a2f2 + acc[r][3] * a2f3;
    parts[to * 65 + ti * 4 + r] = p1;
    parts[1040 + to * 65 + ti * 4 + r] = p2;
  }
  __syncthreads();
  if (t < 64) {
    float s1 = 0.f, s2 = 0.f;
    #pragma unroll
    for (int g = 0; g < 16; ++g) { s1 += parts[g * 65 + t]; s2 += parts[1040 + g * 65 + t]; }
    f1[b * NN + i0 + t] = s1;
    f2[b * NN + i0 + t] = s2;
  }

  #pragma unroll
  for (int r = 0; r < 4; ++r) {
    float lv = level[b * NN + i0 + ti * 4 + r];
    float4 vv;
    vv.x = acc[r][0] * lv; vv.y = acc[r][1] * lv; vv.z = acc[r][2] * lv; vv.w = acc[r][3] * lv;
    *(float4*)&V[(size_t)(b * NN + i0 + ti * 4 + r) * FO + to * 4] = vv;
  }
}

// ---------------- K2: column sums s_j, u (or bitmask), V' fragment pack -----
// grid 256 blocks (b, 64-col j-tile), 512 threads. Reads adj+node_type once.
// STORE_U=1: write u=exp(E) bf16 in row-major [b][i][j] (MFMA-A-ready).
// STORE_U=0: write adjacency bitmask only (small-ws fallback).
template <int STORE_U>
__global__ __launch_bounds__(512) void k2_stats(
    const int* __restrict__ adj,
    const float* __restrict__ ntp,
    const float* __restrict__ f1,
    const float* __restrict__ f2,
    const float* __restrict__ V,
    unsigned short* __restrict__ vf,
    unsigned short* __restrict__ u_bf,
    unsigned char* __restrict__ bits)
{
  __shared__ float red[512 * 9];
  __shared__ float sinv[64];
  int t = threadIdx.x;
  int b = blockIdx.x >> 5;
  int jt = blockIdx.x & 31;
  int j0 = jt * 64;
  int tj = t & 7, isub = t >> 3;
  int j8 = j0 + tj * 8;

  float f2v[8];
  #pragma unroll
  for (int e = 0; e < 8; ++e) f2v[e] = f2[b * NN + j8 + e];
  float acc8[8] = {0, 0, 0, 0, 0, 0, 0, 0};

  for (int i = isub; i < NN; i += 64) {
    size_t base = (size_t)(b * NN + i);
    const int* ap = adj + base * NN + j8;
    int4 a0 = *(const int4*)ap;
    int4 a1 = *(const int4*)(ap + 4);
    const float* npp = ntp + base * NN + j8;
    float4 n0 = *(const float4*)npp;
    float4 n1 = *(const float4*)(npp + 4);
    float f1v = f1[base];
    float ntf[8] = {n0.x, n0.y, n0.z, n0.w, n1.x, n1.y, n1.z, n1.w};
    int am[8] = {a0.x, a0.y, a0.z, a0.w, a1.x, a1.y, a1.z, a1.w};
    float uv[8];
    unsigned int mb = 0;
    #pragma unroll
    for (int e = 0; e < 8; ++e) {
      float x = f1v + f2v[e];
      x = fmaxf(x, 0.2f * x);            // leaky_relu slope 0.2
      float E = x * ntf[e];
      bool m = am[e] > 0;
      float u = m ? __expf(E) : 0.0f;
      uv[e] = u;
      acc8[e] += u;
      mb |= (m ? 1u : 0u) << e;
    }
    if (STORE_U) {
      uint4 pk;
      pk.x = (unsigned int)f2bf(uv[0]) | ((unsigned int)f2bf(uv[1]) << 16);
      pk.y = (unsigned int)f2bf(uv[2]) | ((unsigned int)f2bf(uv[3]) << 16);
      pk.z = (unsigned int)f2bf(uv[4]) | ((unsigned int)f2bf(uv[5]) << 16);
      pk.w = (unsigned int)f2bf(uv[6]) | ((unsigned int)f2bf(uv[7]) << 16);
      *(uint4*)(u_bf + base * NN + j8) = pk;
    } else {
      bits[base * (NN / 8) + jt * 8 + tj] = (unsigned char)mb;
    }
  }

  #pragma unroll
  for (int e = 0; e < 8; ++e) red[t * 9 + e] = acc8[e];
  __syncthreads();
  if (t < 64) {
    int tjj = t >> 3, ee = t & 7;
    float s = 0.f;
    for (int is = 0; is < 64; ++is) s += red[(is * 8 + tjj) * 9 + ee];
    sinv[t] = (s > 0.f) ? (1.0f / s) : 0.0f; // j = j0 + t
  }
  __syncthreads();

  // pack V'[j][o] = V[j][o]/s_j into MFMA B-frag order:
  // vf[(((b*64+kk)*4+ng)*64+l)*8+e] = V'[kk*32+(l>>4)*8+e][ng*16+(l&15)]
  int kl = t >> 8;
  int ng = (t >> 6) & 3;
  int l = t & 63;
  int kk = jt * 2 + kl;
  int jb = kl * 32 + ((l >> 4) * 8);
  int o = ng * 16 + (l & 15);
  unsigned int pk[4];
  #pragma unroll
  for (int p = 0; p < 4; ++p) {
    int jr0 = jb + 2 * p, jr1 = jb + 2 * p + 1;
    float v0 = V[(size_t)(b * NN + j0 + jr0) * FO + o] * sinv[jr0];
    float v1 = V[(size_t)(b * NN + j0 + jr1) * FO + o] * sinv[jr1];
    pk[p] = (unsigned int)f2bf(v0) | ((unsigned int)f2bf(v1) << 16);
  }
  *(uint4*)(vf + (size_t)(((b * 64 + kk) * 4 + ng) * 64 + l) * 8) =
      make_uint4(pk[0], pk[1], pk[2], pk[3]);
}

// ---------------- K3a: out = relu(U @ V'), U preloaded bf16 -----------------
__global__ __launch_bounds__(256) void k3_agg_u(
    const unsigned short* __restrict__ u_bf,
    const unsigned short* __restrict__ vf,
    float* __restrict__ outp)
{
  __shared__ float red[4 * 16 * 68];
  int t = threadIdx.x;
  int b = blockIdx.x >> 7;
  int i0 = (blockIdx.x & 127) * 16;
  int w = t >> 6, l = t & 63;
  int col = l & 15, quad = l >> 4;
  const unsigned short* urow = u_bf + (size_t)(b * NN + i0 + col) * NN + quad * 8;
  const unsigned short* vbase = vf + (size_t)(b * 64) * 2048 + l * 8;
  float4_t acc0 = {0, 0, 0, 0}, acc1 = {0, 0, 0, 0}, acc2 = {0, 0, 0, 0}, acc3 = {0, 0, 0, 0};

  for (int s = 0; s < 16; ++s) {
    int kk = w * 16 + s;
    short8_t A = *(const short8_t*)(urow + kk * 32);
    const unsigned short* vb = vbase + (size_t)kk * 2048;
    short8_t bf0 = *(const short8_t*)(vb);
    short8_t bf1 = *(const short8_t*)(vb + 512);
    short8_t bf2 = *(const short8_t*)(vb + 1024);
    short8_t bf3 = *(const short8_t*)(vb + 1536);
    acc0 = __builtin_amdgcn_mfma_f32_16x16x32_bf16(A, bf0, acc0, 0, 0, 0);
    acc1 = __builtin_amdgcn_mfma_f32_16x16x32_bf16(A, bf1, acc1, 0, 0, 0);
    acc2 = __builtin_amdgcn_mfma_f32_16x16x32_bf16(A, bf2, acc2, 0, 0, 0);
    acc3 = __builtin_amdgcn_mfma_f32_16x16x32_bf16(A, bf3, acc3, 0, 0, 0);
  }

  #pragma unroll
  for (int r = 0; r < 4; ++r) {
    int rowi = quad * 4 + r;
    red[w * 1088 + rowi * 68 + 0 + col] = acc0[r];
    red[w * 1088 + rowi * 68 + 16 + col] = acc1[r];
    red[w * 1088 + rowi * 68 + 32 + col] = acc2[r];
    red[w * 1088 + rowi * 68 + 48 + col] = acc3[r];
  }
  __syncthreads();

  int row = t >> 4, o4 = (t & 15) * 4;
  const float* rp = &red[row * 68 + o4];
  float4 s0 = *(const float4*)(rp);
  float4 s1 = *(const float4*)(rp + 1088);
  float4 s2 = *(const float4*)(rp + 2176);
  float4 s3 = *(const float4*)(rp + 3264);
  float4 o;
  o.x = fmaxf(s0.x + s1.x + s2.x + s3.x, 0.0f);
  o.y = fmaxf(s0.y + s1.y + s2.y + s3.y, 0.0f);
  o.z = fmaxf(s0.z + s1.z + s2.z + s3.z, 0.0f);
  o.w = fmaxf(s0.w + s1.w + s2.w + s3.w, 0.0f);
  *(float4*)&outp[(size_t)(b * NN + i0 + row) * FO + o4] = o;
}

// ---------------- K3b: fallback — recompute u from nt/f1/f2/bits -----------
__global__ __launch_bounds__(256) void k3_agg_b(
    const float* __restrict__ ntp,
    const unsigned char* __restrict__ bits,
    const float* __restrict__ f1,
    const float* __restrict__ f2,
    const unsigned short* __restrict__ vf,
    float* __restrict__ outp)
{
  __shared__ float red[4 * 16 * 68];
  int t = threadIdx.x;
  int b = blockIdx.x >> 7;
  int i0 = (blockIdx.x & 127) * 16;
  int w = t >> 6, l = t & 63;
  int col = l & 15, quad = l >> 4;
  int gi = b * NN + i0 + col;
  float f1v = f1[gi];
  const float* ntrow = ntp + (size_t)gi * NN;
  const unsigned char* brow = bits + (size_t)gi * (NN / 8);
  float4_t acc0 = {0, 0, 0, 0}, acc1 = {0, 0, 0, 0}, acc2 = {0, 0, 0, 0}, acc3 = {0, 0, 0, 0};

  for (int s = 0; s < 16; ++s) {
    int kk = w * 16 + s;
    int jq = kk * 32 + quad * 8;
    unsigned int m8 = brow[jq >> 3];
    float4 n0 = *(const float4*)(ntrow + jq);
    float4 n1 = *(const float4*)(ntrow + jq + 4);
    float4 g0 = *(const float4*)(f2 + b * NN + jq);
    float4 g1 = *(const float4*)(f2 + b * NN + jq + 4);
    float f2v[8] = {g0.x, g0.y, g0.z, g0.w, g1.x, g1.y, g1.z, g1.w};
    float ntf[8] = {n0.x, n0.y, n0.z, n0.w, n1.x, n1.y, n1.z, n1.w};
    union { unsigned int u[4]; short8_t v; } A;
    #pragma unroll
    for (int p = 0; p < 4; ++p) {
      int e0 = 2 * p, e1 = 2 * p + 1;
      float x0 = f1v + f2v[e0]; x0 = fmaxf(x0, 0.2f * x0);
      float u0 = ((m8 >> e0) & 1u) ? __expf(x0 * ntf[e0]) : 0.0f;
      float x1 = f1v + f2v[e1]; x1 = fmaxf(x1, 0.2f * x1);
      float u1 = ((m8 >> e1) & 1u) ? __expf(x1 * ntf[e1]) : 0.0f;
      A.u[p] = (unsigned int)f2bf(u0) | ((unsigned int)f2bf(u1) << 16);
    }
    const unsigned short* vb = vf + (size_t)(b * 64 + kk) * 2048 + l * 8;
    short8_t bf0 = *(const short8_t*)(vb);
    short8_t bf1 = *(const short8_t*)(vb + 512);
    short8_t bf2 = *(const short8_t*)(vb + 1024);
    short8_t bf3 = *(const short8_t*)(vb + 1536);
    acc0 = __builtin_amdgcn_mfma_f32_16x16x32_bf16(A.v, bf0, acc0, 0, 0, 0);
    acc1 = __builtin_amdgcn_mfma_f32_16x16x32_bf16(A.v, bf1, acc1, 0, 0, 0);
    acc2 = __builtin_amdgcn_mfma_f32_16x16x32_bf16(A.v, bf2, acc2, 0, 0, 0);
    acc3 = __builtin_amdgcn_mfma_f32_16x16x32_bf16(A.v, bf3, acc3, 0, 0, 0);
  }

  #pragma unroll
  for (int r = 0; r < 4; ++r) {
    int rowi = quad * 4 + r;
    red[w * 1088 + rowi * 68 + 0 + col] = acc0[r];
    red[w * 1088 + rowi * 68 + 16 + col] = acc1[r];
    red[w * 1088 + rowi * 68 + 32 + col] = acc2[r];
    red[w * 1088 + rowi * 68 + 48 + col] = acc3[r];
  }
  __syncthreads();

  int row = t >> 4, o4 = (t & 15) * 4;
  const float* rp = &red[row * 68 + o4];
  float4 s0 = *(const float4*)(rp);
  float4 s1 = *(const float4*)(rp + 1088);
  float4 s2 = *(const float4*)(rp + 2176);
  float4 s3 = *(const float4*)(rp + 3264);
  float4 o;
  o.x = fmaxf(s0.x + s1.x + s2.x + s3.x, 0.0f);
  o.y = fmaxf(s0.y + s1.y + s2.y + s3.y, 0.0f);
  o.z = fmaxf(s0.z + s1.z + s2.z + s3.z, 0.0f);
  o.w = fmaxf(s0.w + s1.w + s2.w + s3.w, 0.0f);
  *(float4*)&outp[(size_t)(b * NN + i0 + row) * FO + o4] = o;
}

extern "C" void kernel_launch(void* const* d_in, const int* in_sizes, int n_in,
                              void* d_out, int out_size, void* d_ws, size_t ws_size,
                              hipStream_t stream) {
  const float* h = (const float*)d_in[0];       // fp32 [B,N,FIN]
  const int* adj = (const int*)d_in[1];         // int32 [B,N,N]
  const float* level = (const float*)d_in[2];   // fp32 [B,N]
  const float* ntm = (const float*)d_in[3];     // fp32 [B,N,N]
  const float* W = (const float*)d_in[4];       // fp32 [FIN,FO]
  const float* a = (const float*)d_in[5];       // fp32 [2*FO,1]
  float* outp = (float*)d_out;

  float* V = (float*)d_ws;                            // 4 MB
  float* f1 = V + (size_t)BB * NN * FO;               // 64 KB
  float* f2 = f1 + BB * NN;                           // 64 KB
  unsigned short* vf = (unsigned short*)(f2 + BB * NN); // 2 MB
  char* tail = (char*)(vf + (size_t)BB * NN * FO);
  size_t fixed = (size_t)(tail - (char*)d_ws);
  size_t need_u = fixed + (size_t)BB * NN * NN * 2;   // + 67 MB
  bool big = (ws_size >= need_u);

  k1_gemm<<<256, 256, 0, stream>>>(h, level, W, a, V, f1, f2);
  if (big) {
    unsigned short* u_bf = (unsigned short*)tail;
    k2_stats<1><<<256, 512, 0, stream>>>(adj, ntm, f1, f2, V, vf, u_bf, nullptr);
    k3_agg_u<<<1024, 256, 0, stream>>>(u_bf, vf, outp);
  } else {
    unsigned char* bits = (unsigned char*)tail;       // + 4 MB
    k2_stats<0><<<256, 512, 0, stream>>>(adj, ntm, f1, f2, V, vf, nullptr, bits);
    k3_agg_b<<<1024, 256, 0, stream>>>(ntm, bits, f1, f2, vf, outp);
  }
}